// Round 1
// baseline (8419.900 us; speedup 1.0000x reference)
//
#include <hip/hip_runtime.h>
#include <math.h>

// ---------------------------------------------------------------------------
// LocalModel_76527727280750: 6-layer transformer w/ unfold-window attention.
// B=2 S=2048 E=512 H=8 DH=64 W=5 SK=2044 HID=2048 OUT=6 L=6, fp32.
//
// Key algebraic reduction: scores[q,t] = SCALE * sum_w C[q+w-2, t+w] with
// C = Q K^T (DH=64 contraction) -> 4.4x fewer MACs than the 320-dim unfold
// contraction.  v is pre-summed over the window (softmax-independent).
// Attention runs flash-style (online softmax) per (b,h,q-tile of 60).
// ---------------------------------------------------------------------------

namespace {
constexpr int kB   = 2;
constexpr int kS   = 2048;
constexpr int kE   = 512;
constexpr int kH   = 8;
constexpr int kDH  = 64;
constexpr int kSK  = 2044;   // S - W + 1
constexpr int kHID = 2048;
constexpr int kL   = 6;
constexpr float kScale = 0.125f;      // DH^-0.5
constexpr int kTok = kB * kS;         // 4096 rows
constexpr int kNX  = kTok * kE;       // 2,097,152 floats = 8 MB per buffer
}

// ---------------- embedding + sinusoidal positional encoding ----------------
__global__ __launch_bounds__(256) void embed_kernel(const int* __restrict__ idx,
        const float* __restrict__ emb, float* __restrict__ X) {
  const int bs  = blockIdx.x;            // b*S + s
  const int s   = bs & (kS - 1);
  const int tok = idx[bs];
  const int t   = threadIdx.x;
#pragma unroll
  for (int r = 0; r < 2; ++r) {
    const int e = t + 256 * r;
    const int i = e >> 1;
    const float dv  = __expf((float)(2 * i) * (-9.210340371976184f / (float)kE));
    const float ang = (float)s * dv;
    const float pe  = (e & 1) ? cosf(ang) : sinf(ang);   // libm: accurate arg reduction
    X[bs * kE + e] = emb[tok * kE + e] + pe;
  }
}

// ---------------- generic fp32 GEMM: C = act(A@B + bias [+ R]) --------------
// A [M,K] rm, B [K,N] rm. 64x64 tile, 256 thr (16x16), 4x4/thread, K-step 16.
// LDS rows stride 68 floats: 16B-aligned rows AND bank spread (68%8==4).
template <int RELU, int RES>
__global__ __launch_bounds__(256) void gemm_kernel(const float* __restrict__ A,
        const float* __restrict__ Bm, const float* __restrict__ bias,
        const float* __restrict__ Rm, float* __restrict__ C,
        int M, int N, int K) {
  __shared__ float As[16 * 68];   // [kk][i]
  __shared__ float Bs[16 * 68];   // [kk][j]
  const int tid = threadIdx.x;
  const int tx = tid & 15, ty = tid >> 4;
  const int m0 = blockIdx.y * 64, n0 = blockIdx.x * 64;
  const int ka = tid & 15, ia = tid >> 4;   // A-load: k fast (coalesced 64B/16 lanes)
  const int jb = tid & 63, kb = tid >> 6;   // B-load: n fast (coalesced 256B/wave)
  float acc[4][4] = {};
  for (int k0 = 0; k0 < K; k0 += 16) {
#pragma unroll
    for (int r = 0; r < 4; ++r)
      As[ka * 68 + ia + 16 * r] = A[(size_t)(m0 + ia + 16 * r) * K + k0 + ka];
#pragma unroll
    for (int r = 0; r < 4; ++r)
      Bs[(kb + 4 * r) * 68 + jb] = Bm[(size_t)(k0 + kb + 4 * r) * N + n0 + jb];
    __syncthreads();
#pragma unroll
    for (int kk = 0; kk < 16; ++kk) {
      const float4 a4 = *(const float4*)&As[kk * 68 + ty * 4];
      const float4 b4 = *(const float4*)&Bs[kk * 68 + tx * 4];
      const float ar[4] = {a4.x, a4.y, a4.z, a4.w};
      const float br[4] = {b4.x, b4.y, b4.z, b4.w};
#pragma unroll
      for (int r = 0; r < 4; ++r)
#pragma unroll
        for (int c = 0; c < 4; ++c) acc[r][c] = fmaf(ar[r], br[c], acc[r][c]);
    }
    __syncthreads();
  }
  const int nb = n0 + tx * 4;
  const float4 bv = *(const float4*)&bias[nb];
#pragma unroll
  for (int r = 0; r < 4; ++r) {
    const int m = m0 + ty * 4 + r;
    float4 o;
    o.x = acc[r][0] + bv.x; o.y = acc[r][1] + bv.y;
    o.z = acc[r][2] + bv.z; o.w = acc[r][3] + bv.w;
    if (RES) {
      const float4 rv = *(const float4*)&Rm[(size_t)m * N + nb];
      o.x += rv.x; o.y += rv.y; o.z += rv.z; o.w += rv.w;
    }
    if (RELU) {
      o.x = fmaxf(o.x, 0.f); o.y = fmaxf(o.y, 0.f);
      o.z = fmaxf(o.z, 0.f); o.w = fmaxf(o.w, 0.f);
    }
    *(float4*)&C[(size_t)m * N + nb] = o;
  }
}

// ---------------- window pre-sum of V: vs[b,t,e] = sum_{w<5} v[b,t+w,e] -----
__global__ __launch_bounds__(256) void vsum_kernel(const float* __restrict__ V,
        float* __restrict__ VSum) {
  const int gid  = blockIdx.x * 256 + threadIdx.x;   // < B*SK*E (exact)
  const int half = kSK * kE;
  const int b = (gid >= half) ? 1 : 0;
  const int r = gid - b * half;
  const int t = r >> 9, e = r & 511;
  const float* vp = V + (size_t)(b * kS + t) * kE + e;
  VSum[gid] = vp[0] + vp[kE] + vp[2 * kE] + vp[3 * kE] + vp[4 * kE];
}

// ---------------- flash attention with factored shifted scores --------------
// One block per (b,h,q-tile of 60). LDS regions time-multiplexed:
//   R1: Q rows q0-2..q0+61 [i][d] s68 (persistent)
//   R2: K rows t0..t0+63  [j][d] s68  ->  P probs [60][65]
//   R3: C tile [64][68]            ->  Vsum rows [60][64]
// Total static LDS 52.9 KB -> 3 blocks/CU.
__global__ __launch_bounds__(256) void flash_kernel(const float* __restrict__ Q,
        const float* __restrict__ K, const float* __restrict__ VS,
        float* __restrict__ O) {
  const int tid = threadIdx.x;
  const int qt = blockIdx.x, h = blockIdx.y, b = blockIdx.z;
  const int q0 = qt * 60;
  const int cx = tid & 15, cy = tid >> 4;

  __shared__ float R1[64 * 68];
  __shared__ float R2[64 * 68];
  __shared__ float R3[64 * 68];
  __shared__ float mS[60], lS[60], aS[60];

  // load Q tile (rows may be OOB: reference zero-pads q by 2 on each side)
#pragma unroll
  for (int rr = 0; rr < 16; ++rr) {
    const int idx2 = tid + 256 * rr;
    const int i = idx2 >> 6, d = idx2 & 63;
    const int gq = q0 - 2 + i;
    R1[i * 68 + d] = (gq >= 0 && gq < kS)
        ? Q[(size_t)(b * kS + gq) * kE + h * kDH + d] : 0.f;
  }
  if (tid < 60) { mS[tid] = -1e30f; lS[tid] = 0.f; }

  float Oa[4][4] = {};   // rows cy*4+r (cy<15), cols cx*4+c

  for (int t0 = 0; t0 < kSK; t0 += 60) {
    __syncthreads();                                   // prev PV done
    // K tile (rows t0+j, j<64; t+w<=2047 always valid; zero past S)
#pragma unroll
    for (int rr = 0; rr < 16; ++rr) {
      const int idx2 = tid + 256 * rr;
      const int j = idx2 >> 6, d = idx2 & 63;
      const int gk = t0 + j;
      R2[j * 68 + d] = (gk < kS)
          ? K[(size_t)(b * kS + gk) * kE + h * kDH + d] : 0.f;
    }
    __syncthreads();
    // C tile 64x64: thread owns C[4cy+r][cx+16c] (interleaved cols -> 2-way banks)
    float ca[4][4] = {};
#pragma unroll 4
    for (int d0 = 0; d0 < 64; d0 += 4) {
      float4 qv[4], kv[4];
#pragma unroll
      for (int r = 0; r < 4; ++r) qv[r] = *(const float4*)&R1[(cy * 4 + r) * 68 + d0];
#pragma unroll
      for (int c = 0; c < 4; ++c) kv[c] = *(const float4*)&R2[(cx + 16 * c) * 68 + d0];
#pragma unroll
      for (int r = 0; r < 4; ++r)
#pragma unroll
        for (int c = 0; c < 4; ++c)
          ca[r][c] += qv[r].x * kv[c].x + qv[r].y * kv[c].y
                    + qv[r].z * kv[c].z + qv[r].w * kv[c].w;
    }
#pragma unroll
    for (int r = 0; r < 4; ++r)
#pragma unroll
      for (int c = 0; c < 4; ++c)
        R3[(cy * 4 + r) * 68 + cx + 16 * c] = ca[r][c];
    __syncthreads();                                   // C ready; K dead
    // scores: s[ql,tl] = SCALE * sum_w C[ql+w][tl+w]  -> P (R2, stride 65)
#pragma unroll
    for (int rr = 0; rr < 15; ++rr) {
      const int idx2 = tid + 256 * rr;
      const int ql = idx2 >> 6, tl = idx2 & 63;
      if (tl < 60) {
        float sc = R3[ql * 68 + tl]       + R3[(ql + 1) * 68 + tl + 1]
                 + R3[(ql + 2) * 68 + tl + 2] + R3[(ql + 3) * 68 + tl + 3]
                 + R3[(ql + 4) * 68 + tl + 4];
        sc *= kScale;
        if (t0 + tl >= kSK) sc = -1e30f;
        R2[ql * 65 + tl] = sc;
      }
    }
    __syncthreads();                                   // P ready; C dead
    if (tid < 64) {
      if (tid < 60) {        // online softmax, one row per lane (wave 0)
        const float mold = mS[tid];
        float mrow = mold;
        for (int tt = 0; tt < 60; ++tt) mrow = fmaxf(mrow, R2[tid * 65 + tt]);
        const float al = __expf(mold - mrow);
        float ls = 0.f;
        for (int tt = 0; tt < 60; ++tt) {
          const float p = __expf(R2[tid * 65 + tt] - mrow);
          R2[tid * 65 + tt] = p;
          ls += p;
        }
        mS[tid] = mrow;
        lS[tid] = lS[tid] * al + ls;
        aS[tid] = al;
      }
    } else {                 // waves 1..3 load Vsum tile into R3 meanwhile
      const int t2 = tid - 64;
#pragma unroll
      for (int rr = 0; rr < 20; ++rr) {
        const int idx2 = t2 + 192 * rr;
        const int tl = idx2 >> 6, d = idx2 & 63;
        const int gt = t0 + tl;
        R3[tl * 64 + d] = (gt < kSK)
            ? VS[(size_t)(b * kSK + gt) * kE + h * kDH + d] : 0.f;
      }
    }
    __syncthreads();
    // rescale + PV:  O[ql][d] = O*alpha + P @ Vsum
    if (cy < 15) {
      const float a0 = aS[cy * 4 + 0], a1 = aS[cy * 4 + 1];
      const float a2 = aS[cy * 4 + 2], a3 = aS[cy * 4 + 3];
#pragma unroll
      for (int c = 0; c < 4; ++c) {
        Oa[0][c] *= a0; Oa[1][c] *= a1; Oa[2][c] *= a2; Oa[3][c] *= a3;
      }
#pragma unroll 4
      for (int tl = 0; tl < 60; ++tl) {
        const float4 vv = *(const float4*)&R3[tl * 64 + cx * 4];
        const float p0 = R2[(cy * 4 + 0) * 65 + tl];
        const float p1 = R2[(cy * 4 + 1) * 65 + tl];
        const float p2 = R2[(cy * 4 + 2) * 65 + tl];
        const float p3 = R2[(cy * 4 + 3) * 65 + tl];
        Oa[0][0] += p0 * vv.x; Oa[0][1] += p0 * vv.y; Oa[0][2] += p0 * vv.z; Oa[0][3] += p0 * vv.w;
        Oa[1][0] += p1 * vv.x; Oa[1][1] += p1 * vv.y; Oa[1][2] += p1 * vv.z; Oa[1][3] += p1 * vv.w;
        Oa[2][0] += p2 * vv.x; Oa[2][1] += p2 * vv.y; Oa[2][2] += p2 * vv.z; Oa[2][3] += p2 * vv.w;
        Oa[3][0] += p3 * vv.x; Oa[3][1] += p3 * vv.y; Oa[3][2] += p3 * vv.z; Oa[3][3] += p3 * vv.w;
      }
    }
  }
  if (cy < 15) {
#pragma unroll
    for (int r = 0; r < 4; ++r) {
      const int q = q0 + cy * 4 + r;
      if (q < kS) {
        const float inv = 1.f / lS[cy * 4 + r];
        float4 o4;
        o4.x = Oa[r][0] * inv; o4.y = Oa[r][1] * inv;
        o4.z = Oa[r][2] * inv; o4.w = Oa[r][3] * inv;
        *(float4*)&O[(size_t)(b * kS + q) * kE + h * kDH + cx * 4] = o4;
      }
    }
  }
}

// ---------------- layernorm over E=512 (one block per row) ------------------
__global__ __launch_bounds__(256) void ln_kernel(const float* __restrict__ Xin,
        const float* __restrict__ w, const float* __restrict__ bb,
        float* __restrict__ Y) {
  const int row = blockIdx.x;
  const int tid = threadIdx.x;
  const float* xr = Xin + (size_t)row * kE;
  const float v0 = xr[tid], v1 = xr[tid + 256];
  float s = v0 + v1, sq = v0 * v0 + v1 * v1;
  for (int off = 32; off; off >>= 1) {
    s  += __shfl_down(s, off);
    sq += __shfl_down(sq, off);
  }
  __shared__ float rs[4], rq[4];
  const int wid = tid >> 6;
  if ((tid & 63) == 0) { rs[wid] = s; rq[wid] = sq; }
  __syncthreads();
  const float St = rs[0] + rs[1] + rs[2] + rs[3];
  const float Qt = rq[0] + rq[1] + rq[2] + rq[3];
  const float mean = St * (1.f / kE);
  const float var  = Qt * (1.f / kE) - mean * mean;
  const float rstd = rsqrtf(var + 1e-5f);
  float* yr = Y + (size_t)row * kE;
  yr[tid]       = (v0 - mean) * rstd * w[tid]       + bb[tid];
  yr[tid + 256] = (v1 - mean) * rstd * w[tid + 256] + bb[tid + 256];
}

// ---------------- final head: out[b,o] = sum_k x[b,k] W[k,o] + b[o] ---------
__global__ __launch_bounds__(256) void final_kernel(const float* __restrict__ X,
        const float* __restrict__ Wt, const float* __restrict__ bias,
        float* __restrict__ out) {
  const int b = blockIdx.y, chunk = blockIdx.x;
  const int tid = threadIdx.x;
  const float* xb = X + (size_t)b * (kS * kE);
  float acc[6] = {};
  const int k0 = chunk * 8192;                     // 128 chunks * 8192 = 1M
#pragma unroll 4
  for (int i = 0; i < 32; ++i) {
    const int kk = k0 + tid + i * 256;
    const float xv = xb[kk];
    const float* wr = Wt + (size_t)kk * 6;
#pragma unroll
    for (int o = 0; o < 6; ++o) acc[o] = fmaf(xv, wr[o], acc[o]);
  }
#pragma unroll
  for (int o = 0; o < 6; ++o)
    for (int off = 32; off; off >>= 1) acc[o] += __shfl_down(acc[o], off);
  __shared__ float part[4][6];
  const int wid = tid >> 6;
  if ((tid & 63) == 0) {
#pragma unroll
    for (int o = 0; o < 6; ++o) part[wid][o] = acc[o];
  }
  __syncthreads();
  if (tid < 6) {
    float s2 = part[0][tid] + part[1][tid] + part[2][tid] + part[3][tid];
    if (chunk == 0) s2 += bias[tid];
    atomicAdd(&out[b * 6 + tid], s2);
  }
}

// ---------------------------------------------------------------------------
extern "C" void kernel_launch(void* const* d_in, const int* in_sizes, int n_in,
                              void* d_out, int out_size, void* d_ws, size_t ws_size,
                              hipStream_t stream) {
  (void)in_sizes; (void)n_in; (void)ws_size;
  const int*   tok   = (const int*)d_in[0];
  const float* emb   = (const float*)d_in[1];
  const float* ln_w  = (const float*)d_in[2];
  const float* ln_b  = (const float*)d_in[3];
  const float* q_w   = (const float*)d_in[4];
  const float* q_b   = (const float*)d_in[5];
  const float* k_w   = (const float*)d_in[6];
  const float* k_b   = (const float*)d_in[7];
  const float* v_w   = (const float*)d_in[8];
  const float* v_b   = (const float*)d_in[9];
  const float* fc1_w = (const float*)d_in[10];
  const float* fc1_b = (const float*)d_in[11];
  const float* fc2_w = (const float*)d_in[12];
  const float* fc2_b = (const float*)d_in[13];
  const float* out_w = (const float*)d_in[14];
  const float* out_b = (const float*)d_in[15];

  // workspace layout (floats): 6 regions of kNX; FFN hidden aliases q..vs.
  float* ws   = (float*)d_ws;
  float* x    = ws;                         // [B,S,E]
  float* y    = ws + (size_t)1 * kNX;       // [B,S,E]
  float* q    = ws + (size_t)2 * kNX;
  float* k    = ws + (size_t)3 * kNX;
  float* v    = ws + (size_t)4 * kNX;
  float* vs   = ws + (size_t)5 * kNX;       // [B,SK,E]
  float* hbuf = ws + (size_t)2 * kNX;       // [B*S,HID] aliases q/k/v/vs (dead)

  embed_kernel<<<dim3(kTok), 256, 0, stream>>>(tok, emb, x);
  for (int l = 0; l < kL; ++l) {
    gemm_kernel<0, 0><<<dim3(kE / 64, kTok / 64), 256, 0, stream>>>(
        x, q_w, q_b, nullptr, q, kTok, kE, kE);
    gemm_kernel<0, 0><<<dim3(kE / 64, kTok / 64), 256, 0, stream>>>(
        x, k_w, k_b, nullptr, k, kTok, kE, kE);
    gemm_kernel<0, 0><<<dim3(kE / 64, kTok / 64), 256, 0, stream>>>(
        x, v_w, v_b, nullptr, v, kTok, kE, kE);
    vsum_kernel<<<dim3((kB * kSK * kE) / 256), 256, 0, stream>>>(v, vs);
    flash_kernel<<<dim3(35, kH, kB), 256, 0, stream>>>(q, k, vs, y);
    ln_kernel<<<dim3(kTok), 256, 0, stream>>>(y, ln_w, ln_b, x);
    gemm_kernel<1, 0><<<dim3(kHID / 64, kTok / 64), 256, 0, stream>>>(
        x, fc1_w, fc1_b, nullptr, hbuf, kTok, kHID, kE);
    gemm_kernel<0, 1><<<dim3(kE / 64, kTok / 64), 256, 0, stream>>>(
        hbuf, fc2_w, fc2_b, x, y, kTok, kE, kHID);
    ln_kernel<<<dim3(kTok), 256, 0, stream>>>(y, ln_w, ln_b, x);
  }
  hipMemsetAsync(d_out, 0, (size_t)out_size * sizeof(float), stream);
  final_kernel<<<dim3(128, kB), 256, 0, stream>>>(x, out_w, out_b, (float*)d_out);
}

// Round 2
// 6707.816 us; speedup vs baseline: 1.2552x; 1.2552x over previous
//
#include <hip/hip_runtime.h>
#include <math.h>

// ---------------------------------------------------------------------------
// LocalModel_76527727280750: 6-layer transformer w/ unfold-window attention.
// B=2 S=2048 E=512 H=8 DH=64 W=5 SK=2044 HID=2048 OUT=6 L=6, fp32 in/out.
//
// R2: dense GEMMs moved to bf16 MFMA (16x16x32), weights transpose-cast to
// bf16 [N][K] per launch, q/k/v fused into one N=1536 GEMM. Flash softmax
// parallelized (4 lanes/row instead of 1 wave total).
// ---------------------------------------------------------------------------

namespace {
constexpr int kB   = 2;
constexpr int kS   = 2048;
constexpr int kE   = 512;
constexpr int kH   = 8;
constexpr int kDH  = 64;
constexpr int kSK  = 2044;   // S - W + 1
constexpr int kHID = 2048;
constexpr int kL   = 6;
constexpr float kScale = 0.125f;      // DH^-0.5
constexpr int kTok = kB * kS;         // 4096 rows
constexpr int kNX  = kTok * kE;       // 2,097,152 floats = 8 MB per buffer
constexpr int kQKV = 3 * kE;          // 1536 fused row stride
}

typedef __attribute__((ext_vector_type(8))) short short8;
typedef __attribute__((ext_vector_type(4))) float floatx4;

static __device__ __forceinline__ unsigned short f2bf(float f) {
  unsigned int u = __float_as_uint(f);
  u += 0x7fffu + ((u >> 16) & 1u);     // RTNE
  return (unsigned short)(u >> 16);
}

// ---------------- embedding + sinusoidal positional encoding ----------------
__global__ __launch_bounds__(256) void embed_kernel(const int* __restrict__ idx,
        const float* __restrict__ emb, float* __restrict__ X) {
  const int bs  = blockIdx.x;            // b*S + s
  const int s   = bs & (kS - 1);
  const int tok = idx[bs];
  const int t   = threadIdx.x;
#pragma unroll
  for (int r = 0; r < 2; ++r) {
    const int e = t + 256 * r;
    const int i = e >> 1;
    const float dv  = __expf((float)(2 * i) * (-9.210340371976184f / (float)kE));
    const float ang = (float)s * dv;
    const float pe  = (e & 1) ? cosf(ang) : sinf(ang);   // libm: accurate arg reduction
    X[bs * kE + e] = emb[tok * kE + e] + pe;
  }
}

// ---------------- weight transpose-cast: fp32 [K][N] -> bf16 [N][K] ---------
__global__ __launch_bounds__(256) void tcast_kernel(const float* __restrict__ src,
        unsigned short* __restrict__ dst, int K, int N) {
  __shared__ float t[32][33];
  const int tid = threadIdx.x;
  const int tx = tid & 31, ty = tid >> 5;          // 32 x 8
  const int n0 = blockIdx.x * 32, k0 = blockIdx.y * 32;
#pragma unroll
  for (int p = 0; p < 4; ++p)
    t[ty + 8 * p][tx] = src[(size_t)(k0 + ty + 8 * p) * N + n0 + tx];
  __syncthreads();
#pragma unroll
  for (int p = 0; p < 4; ++p)
    dst[(size_t)(n0 + ty + 8 * p) * K + k0 + tx] = f2bf(t[tx][ty + 8 * p]);
}

__global__ __launch_bounds__(256) void qkvb_kernel(const float* __restrict__ qb,
        const float* __restrict__ kb, const float* __restrict__ vb,
        float* __restrict__ dst) {
  const int i = blockIdx.x * 256 + threadIdx.x;    // grid 6 -> 1536
  dst[i] = (i < 512) ? qb[i] : ((i < 1024) ? kb[i - 512] : vb[i - 1024]);
}

// ---------------- bf16 MFMA GEMM: C = act(A@B + bias [+ R]) -----------------
// A fp32 [M,K] (cast to bf16 at staging), Bt bf16 [N,K] (pre-transposed).
// 128x128 tile, 4 waves (2x2 quadrants of 64x64), K-step 32.
// LDS rows stride 40 bf16 = 80 B: 16B-aligned, frag b128 reads exactly 2-way.
template <int RELU, int RES>
__global__ __launch_bounds__(256) void mfma_gemm(const float* __restrict__ A,
        const unsigned short* __restrict__ Bt, const float* __restrict__ bias,
        const float* __restrict__ Rm, float* __restrict__ C,
        int M, int N, int K) {
  __shared__ __align__(16) unsigned short As[128 * 40];
  __shared__ __align__(16) unsigned short Bs[128 * 40];
  const int tid = threadIdx.x;
  const int m0 = blockIdx.y * 128, n0 = blockIdx.x * 128;
  const int wid = tid >> 6, lane = tid & 63;
  const int lm = lane & 15, quad = lane >> 4;
  const int wm = (wid & 1) * 64, wn = (wid >> 1) * 64;
  const int am = tid >> 3, ak = (tid & 7) * 4;     // A staging: 32 rows/pass
  const int bn = tid >> 2, bk = (tid & 3) * 8;     // B staging: 64 rows/pass
  floatx4 acc[4][4] = {};
  for (int k0 = 0; k0 < K; k0 += 32) {
#pragma unroll
    for (int p = 0; p < 4; ++p) {
      const float4 v = *(const float4*)&A[(size_t)(m0 + am + 32 * p) * K + k0 + ak];
      ushort4 o;
      o.x = f2bf(v.x); o.y = f2bf(v.y); o.z = f2bf(v.z); o.w = f2bf(v.w);
      *(ushort4*)&As[(am + 32 * p) * 40 + ak] = o;
    }
#pragma unroll
    for (int p = 0; p < 2; ++p) {
      const uint4 v = *(const uint4*)&Bt[(size_t)(n0 + bn + 64 * p) * K + k0 + bk];
      *(uint4*)&Bs[(bn + 64 * p) * 40 + bk] = v;
    }
    __syncthreads();
    short8 af[4], bf[4];
#pragma unroll
    for (int t = 0; t < 4; ++t) {
      af[t] = *(const short8*)&As[(wm + t * 16 + lm) * 40 + quad * 8];
      bf[t] = *(const short8*)&Bs[(wn + t * 16 + lm) * 40 + quad * 8];
    }
#pragma unroll
    for (int mt = 0; mt < 4; ++mt)
#pragma unroll
      for (int nt = 0; nt < 4; ++nt)
        acc[mt][nt] = __builtin_amdgcn_mfma_f32_16x16x32_bf16(
            af[mt], bf[nt], acc[mt][nt], 0, 0, 0);
    __syncthreads();
  }
  // epilogue: D col = lane&15 (n), row = quad*4+reg (m)  [verified layout]
#pragma unroll
  for (int mt = 0; mt < 4; ++mt) {
#pragma unroll
    for (int nt = 0; nt < 4; ++nt) {
      const int n = n0 + wn + nt * 16 + lm;
      const float bv = bias[n];
#pragma unroll
      for (int r = 0; r < 4; ++r) {
        const int m = m0 + wm + mt * 16 + quad * 4 + r;
        float o = acc[mt][nt][r] + bv;
        if (RES) o += Rm[(size_t)m * N + n];
        if (RELU) o = fmaxf(o, 0.f);
        C[(size_t)m * N + n] = o;
      }
    }
  }
}

// ---------------- window pre-sum of V (inside fused qkv buffer) -------------
__global__ __launch_bounds__(256) void vsum_kernel(const float* __restrict__ QKV,
        float* __restrict__ VSum) {
  const int gid  = blockIdx.x * 256 + threadIdx.x;   // < B*SK*E (exact)
  const int half = kSK * kE;
  const int b = (gid >= half) ? 1 : 0;
  const int r = gid - b * half;
  const int t = r >> 9, e = r & 511;
  const float* vp = QKV + (size_t)(b * kS + t) * kQKV + 2 * kE + e;
  VSum[gid] = vp[0] + vp[kQKV] + vp[2 * kQKV] + vp[3 * kQKV] + vp[4 * kQKV];
}

// ---------------- flash attention with factored shifted scores --------------
// One block per (b,h,q-tile of 60). LDS regions time-multiplexed:
//   R1: Q rows q0-2..q0+61 [i][d] s68 (persistent)
//   R2: K rows t0..t0+63  [j][d] s68  ->  P probs [60][65]
//   R3: C tile [64][68]            ->  Vsum rows [60][64]
__global__ __launch_bounds__(256) void flash_kernel(const float* __restrict__ QKV,
        const float* __restrict__ VS, float* __restrict__ O) {
  const int tid = threadIdx.x;
  const int qt = blockIdx.x, h = blockIdx.y, b = blockIdx.z;
  const int q0 = qt * 60;
  const int cx = tid & 15, cy = tid >> 4;

  __shared__ float R1[64 * 68];
  __shared__ float R2[64 * 68];
  __shared__ float R3[64 * 68];
  __shared__ float mS[60], lS[60], aS[60];

  // load Q tile (rows may be OOB: reference zero-pads q by 2 on each side)
#pragma unroll
  for (int rr = 0; rr < 16; ++rr) {
    const int idx2 = tid + 256 * rr;
    const int i = idx2 >> 6, d = idx2 & 63;
    const int gq = q0 - 2 + i;
    R1[i * 68 + d] = (gq >= 0 && gq < kS)
        ? QKV[(size_t)(b * kS + gq) * kQKV + h * kDH + d] : 0.f;
  }
  if (tid < 60) { mS[tid] = -1e30f; lS[tid] = 0.f; }

  float Oa[4][4] = {};   // rows cy*4+r (cy<15), cols cx*4+c

  for (int t0 = 0; t0 < kSK; t0 += 60) {
    __syncthreads();                                   // prev PV done
    // K tile (rows t0+j, j<64)
#pragma unroll
    for (int rr = 0; rr < 16; ++rr) {
      const int idx2 = tid + 256 * rr;
      const int j = idx2 >> 6, d = idx2 & 63;
      const int gk = t0 + j;
      R2[j * 68 + d] = (gk < kS)
          ? QKV[(size_t)(b * kS + gk) * kQKV + kE + h * kDH + d] : 0.f;
    }
    __syncthreads();
    // C tile 64x64: thread owns C[4cy+r][cx+16c] (interleaved cols -> 2-way banks)
    float ca[4][4] = {};
#pragma unroll 4
    for (int d0 = 0; d0 < 64; d0 += 4) {
      float4 qv[4], kv[4];
#pragma unroll
      for (int r = 0; r < 4; ++r) qv[r] = *(const float4*)&R1[(cy * 4 + r) * 68 + d0];
#pragma unroll
      for (int c = 0; c < 4; ++c) kv[c] = *(const float4*)&R2[(cx + 16 * c) * 68 + d0];
#pragma unroll
      for (int r = 0; r < 4; ++r)
#pragma unroll
        for (int c = 0; c < 4; ++c)
          ca[r][c] += qv[r].x * kv[c].x + qv[r].y * kv[c].y
                    + qv[r].z * kv[c].z + qv[r].w * kv[c].w;
    }
#pragma unroll
    for (int r = 0; r < 4; ++r)
#pragma unroll
      for (int c = 0; c < 4; ++c)
        R3[(cy * 4 + r) * 68 + cx + 16 * c] = ca[r][c];
    __syncthreads();                                   // C ready; K dead
    // scores: s[ql,tl] = SCALE * sum_w C[ql+w][tl+w]  -> P (R2, stride 65)
#pragma unroll
    for (int rr = 0; rr < 15; ++rr) {
      const int idx2 = tid + 256 * rr;
      const int ql = idx2 >> 6, tl = idx2 & 63;
      if (tl < 60) {
        float sc = R3[ql * 68 + tl]       + R3[(ql + 1) * 68 + tl + 1]
                 + R3[(ql + 2) * 68 + tl + 2] + R3[(ql + 3) * 68 + tl + 3]
                 + R3[(ql + 4) * 68 + tl + 4];
        sc *= kScale;
        if (t0 + tl >= kSK) sc = -1e30f;
        R2[ql * 65 + tl] = sc;
      }
    }
    __syncthreads();                                   // P(scores) ready; C dead
    // online softmax: 4 lanes per row (row = tid>>2, seg = tid&3, 15 cols each)
    {
      const int r = tid >> 2, seg = tid & 3;
      if (r < 60) {
        const float mold = mS[r];
        float mrow = mold;
        const int c0 = seg * 15;
        for (int tt = 0; tt < 15; ++tt) mrow = fmaxf(mrow, R2[r * 65 + c0 + tt]);
        mrow = fmaxf(mrow, __shfl_xor(mrow, 1));
        mrow = fmaxf(mrow, __shfl_xor(mrow, 2));
        float ls = 0.f;
        for (int tt = 0; tt < 15; ++tt) {
          const float p = __expf(R2[r * 65 + c0 + tt] - mrow);
          R2[r * 65 + c0 + tt] = p;
          ls += p;
        }
        ls += __shfl_xor(ls, 1);
        ls += __shfl_xor(ls, 2);
        if (seg == 0) {
          const float al = __expf(mold - mrow);
          aS[r] = al; mS[r] = mrow; lS[r] = lS[r] * al + ls;
        }
      }
    }
    __syncthreads();                                   // probs/aS ready; C dead
    // Vsum tile load (all 256 threads): 60*64 = 3840 = 15*256
#pragma unroll
    for (int rr = 0; rr < 15; ++rr) {
      const int idx2 = tid + 256 * rr;
      const int tl = idx2 >> 6, d = idx2 & 63;
      const int gt = t0 + tl;
      R3[tl * 64 + d] = (gt < kSK)
          ? VS[(size_t)(b * kSK + gt) * kE + h * kDH + d] : 0.f;
    }
    __syncthreads();
    // rescale + PV:  O[ql][d] = O*alpha + P @ Vsum
    if (cy < 15) {
      const float a0 = aS[cy * 4 + 0], a1 = aS[cy * 4 + 1];
      const float a2 = aS[cy * 4 + 2], a3 = aS[cy * 4 + 3];
#pragma unroll
      for (int c = 0; c < 4; ++c) {
        Oa[0][c] *= a0; Oa[1][c] *= a1; Oa[2][c] *= a2; Oa[3][c] *= a3;
      }
#pragma unroll 4
      for (int tl = 0; tl < 60; ++tl) {
        const float4 vv = *(const float4*)&R3[tl * 64 + cx * 4];
        const float p0 = R2[(cy * 4 + 0) * 65 + tl];
        const float p1 = R2[(cy * 4 + 1) * 65 + tl];
        const float p2 = R2[(cy * 4 + 2) * 65 + tl];
        const float p3 = R2[(cy * 4 + 3) * 65 + tl];
        Oa[0][0] += p0 * vv.x; Oa[0][1] += p0 * vv.y; Oa[0][2] += p0 * vv.z; Oa[0][3] += p0 * vv.w;
        Oa[1][0] += p1 * vv.x; Oa[1][1] += p1 * vv.y; Oa[1][2] += p1 * vv.z; Oa[1][3] += p1 * vv.w;
        Oa[2][0] += p2 * vv.x; Oa[2][1] += p2 * vv.y; Oa[2][2] += p2 * vv.z; Oa[2][3] += p2 * vv.w;
        Oa[3][0] += p3 * vv.x; Oa[3][1] += p3 * vv.y; Oa[3][2] += p3 * vv.z; Oa[3][3] += p3 * vv.w;
      }
    }
  }
  if (cy < 15) {
#pragma unroll
    for (int r = 0; r < 4; ++r) {
      const int q = q0 + cy * 4 + r;
      if (q < kS) {
        const float inv = 1.f / lS[cy * 4 + r];
        float4 o4;
        o4.x = Oa[r][0] * inv; o4.y = Oa[r][1] * inv;
        o4.z = Oa[r][2] * inv; o4.w = Oa[r][3] * inv;
        *(float4*)&O[(size_t)(b * kS + q) * kE + h * kDH + cx * 4] = o4;
      }
    }
  }
}

// ---------------- layernorm over E=512 (one block per row) ------------------
__global__ __launch_bounds__(256) void ln_kernel(const float* __restrict__ Xin,
        const float* __restrict__ w, const float* __restrict__ bb,
        float* __restrict__ Y) {
  const int row = blockIdx.x;
  const int tid = threadIdx.x;
  const float* xr = Xin + (size_t)row * kE;
  const float v0 = xr[tid], v1 = xr[tid + 256];
  float s = v0 + v1, sq = v0 * v0 + v1 * v1;
  for (int off = 32; off; off >>= 1) {
    s  += __shfl_down(s, off);
    sq += __shfl_down(sq, off);
  }
  __shared__ float rs[4], rq[4];
  const int wid = tid >> 6;
  if ((tid & 63) == 0) { rs[wid] = s; rq[wid] = sq; }
  __syncthreads();
  const float St = rs[0] + rs[1] + rs[2] + rs[3];
  const float Qt = rq[0] + rq[1] + rq[2] + rq[3];
  const float mean = St * (1.f / kE);
  const float var  = Qt * (1.f / kE) - mean * mean;
  const float rstd = rsqrtf(var + 1e-5f);
  float* yr = Y + (size_t)row * kE;
  yr[tid]       = (v0 - mean) * rstd * w[tid]       + bb[tid];
  yr[tid + 256] = (v1 - mean) * rstd * w[tid + 256] + bb[tid + 256];
}

// ---------------- final head: out[b,o] = sum_k x[b,k] W[k,o] + b[o] ---------
__global__ __launch_bounds__(256) void final_kernel(const float* __restrict__ X,
        const float* __restrict__ Wt, const float* __restrict__ bias,
        float* __restrict__ out) {
  const int b = blockIdx.y, chunk = blockIdx.x;
  const int tid = threadIdx.x;
  const float* xb = X + (size_t)b * (kS * kE);
  float acc[6] = {};
  const int k0 = chunk * 8192;                     // 128 chunks * 8192 = 1M
#pragma unroll 4
  for (int i = 0; i < 32; ++i) {
    const int kk = k0 + tid + i * 256;
    const float xv = xb[kk];
    const float* wr = Wt + (size_t)kk * 6;
#pragma unroll
    for (int o = 0; o < 6; ++o) acc[o] = fmaf(xv, wr[o], acc[o]);
  }
#pragma unroll
  for (int o = 0; o < 6; ++o)
    for (int off = 32; off; off >>= 1) acc[o] += __shfl_down(acc[o], off);
  __shared__ float part[4][6];
  const int wid = tid >> 6;
  if ((tid & 63) == 0) {
#pragma unroll
    for (int o = 0; o < 6; ++o) part[wid][o] = acc[o];
  }
  __syncthreads();
  if (tid < 6) {
    float s2 = part[0][tid] + part[1][tid] + part[2][tid] + part[3][tid];
    if (chunk == 0) s2 += bias[tid];
    atomicAdd(&out[b * 6 + tid], s2);
  }
}

// ---------------------------------------------------------------------------
extern "C" void kernel_launch(void* const* d_in, const int* in_sizes, int n_in,
                              void* d_out, int out_size, void* d_ws, size_t ws_size,
                              hipStream_t stream) {
  (void)in_sizes; (void)n_in; (void)ws_size;
  const int*   tok   = (const int*)d_in[0];
  const float* emb   = (const float*)d_in[1];
  const float* ln_w  = (const float*)d_in[2];
  const float* ln_b  = (const float*)d_in[3];
  const float* q_w   = (const float*)d_in[4];
  const float* q_b   = (const float*)d_in[5];
  const float* k_w   = (const float*)d_in[6];
  const float* k_b   = (const float*)d_in[7];
  const float* v_w   = (const float*)d_in[8];
  const float* v_b   = (const float*)d_in[9];
  const float* fc1_w = (const float*)d_in[10];
  const float* fc1_b = (const float*)d_in[11];
  const float* fc2_w = (const float*)d_in[12];
  const float* fc2_b = (const float*)d_in[13];
  const float* out_w = (const float*)d_in[14];
  const float* out_b = (const float*)d_in[15];

  // workspace layout (floats):
  //   x [4096,512] | y [4096,512] | vs [B,SK,512] | regA (8M floats = 32 MB):
  //     qkv [4096,1536] (first 6M) / hbuf [4096,2048] (aliases, qkv dead by fc1)
  //   then bf16 weights + fused bias.
  float* ws   = (float*)d_ws;
  float* x    = ws;
  float* y    = ws + (size_t)1 * kNX;
  float* vs   = ws + (size_t)2 * kNX;
  float* regA = ws + (size_t)3 * kNX;       // 8M floats
  float* qkv  = regA;                        // [4096][1536]
  float* hbuf = regA;                        // [4096][2048] (after attention)
  unsigned short* wqkvT = (unsigned short*)(ws + (size_t)7 * kNX);  // [1536][512]
  unsigned short* fc1T  = wqkvT + (size_t)kQKV * kE;                // [2048][512]
  unsigned short* fc2T  = fc1T + (size_t)kHID * kE;                 // [512][2048]
  float* qkvb = (float*)(fc2T + (size_t)kE * kHID);                 // [1536]

  // per-launch weight prep (no static guards; graph-safe)
  tcast_kernel<<<dim3(16, 16), 256, 0, stream>>>(q_w, wqkvT, kE, kE);
  tcast_kernel<<<dim3(16, 16), 256, 0, stream>>>(k_w, wqkvT + (size_t)kE * kE, kE, kE);
  tcast_kernel<<<dim3(16, 16), 256, 0, stream>>>(v_w, wqkvT + (size_t)2 * kE * kE, kE, kE);
  tcast_kernel<<<dim3(64, 16), 256, 0, stream>>>(fc1_w, fc1T, kE, kHID);
  tcast_kernel<<<dim3(16, 64), 256, 0, stream>>>(fc2_w, fc2T, kHID, kE);
  qkvb_kernel<<<dim3(6), 256, 0, stream>>>(q_b, k_b, v_b, qkvb);

  embed_kernel<<<dim3(kTok), 256, 0, stream>>>(tok, emb, x);
  for (int l = 0; l < kL; ++l) {
    mfma_gemm<0, 0><<<dim3(kQKV / 128, kTok / 128), 256, 0, stream>>>(
        x, wqkvT, qkvb, nullptr, qkv, kTok, kQKV, kE);
    vsum_kernel<<<dim3((kB * kSK * kE) / 256), 256, 0, stream>>>(qkv, vs);
    flash_kernel<<<dim3(35, kH, kB), 256, 0, stream>>>(qkv, vs, y);
    ln_kernel<<<dim3(kTok), 256, 0, stream>>>(y, ln_w, ln_b, x);
    mfma_gemm<1, 0><<<dim3(kHID / 128, kTok / 128), 256, 0, stream>>>(
        x, fc1T, fc1_b, nullptr, hbuf, kTok, kHID, kE);
    mfma_gemm<0, 1><<<dim3(kE / 128, kTok / 128), 256, 0, stream>>>(
        hbuf, fc2T, fc2_b, x, y, kTok, kE, kHID);
    ln_kernel<<<dim3(kTok), 256, 0, stream>>>(y, ln_w, ln_b, x);
  }
  hipMemsetAsync(d_out, 0, (size_t)out_size * sizeof(float), stream);
  final_kernel<<<dim3(128, kB), 256, 0, stream>>>(x, out_w, out_b, (float*)d_out);
}

// Round 3
// 1973.172 us; speedup vs baseline: 4.2672x; 3.3995x over previous
//
#include <hip/hip_runtime.h>
#include <math.h>

// ---------------------------------------------------------------------------
// LocalModel_76527727280750: 6-layer transformer w/ unfold-window attention.
// B=2 S=2048 E=512 H=8 DH=64 W=5 SK=2044 HID=2048 OUT=6 L=6, fp32 in/out.
//
// R3: flash attention rewritten on MFMA using the *unfold* identity:
//   scores[q,t] = SCALE * sum_w Q[q+w-2]. K[t+w]   (320-dim contraction)
// The unfold is pure LDS row-offset addressing (no C-tile round trip, no
// shift phase). Each wave owns a 16-row score strip -> in-register online
// softmax; P->LDS round trip is wave-private (no barrier). All attention
// math in fp16 MFMA (fp32 accum). 2 barriers/iter, 32 iters.
// ---------------------------------------------------------------------------

namespace {
constexpr int kB   = 2;
constexpr int kS   = 2048;
constexpr int kE   = 512;
constexpr int kH   = 8;
constexpr int kDH  = 64;
constexpr int kSK  = 2044;   // S - W + 1
constexpr int kHID = 2048;
constexpr int kL   = 6;
constexpr float kScale = 0.125f;      // DH^-0.5
constexpr int kTok = kB * kS;         // 4096 rows
constexpr int kNX  = kTok * kE;       // 2,097,152 floats = 8 MB per buffer
constexpr int kQKV = 3 * kE;          // 1536 fused row stride
constexpr int kSQ  = 72;              // flash LDS row stride (f16 elems)
}

using f16x8   = __attribute__((ext_vector_type(8))) _Float16;
using floatx4 = __attribute__((ext_vector_type(4))) float;

static __device__ __forceinline__ unsigned short f2h(float f) {
  return __builtin_bit_cast(unsigned short, (_Float16)f);
}
static __device__ __forceinline__ float h2f(unsigned short u) {
  return (float)__builtin_bit_cast(_Float16, u);
}

// ---------------- embedding + sinusoidal positional encoding ----------------
__global__ __launch_bounds__(256) void embed_kernel(const int* __restrict__ idx,
        const float* __restrict__ emb, float* __restrict__ X) {
  const int bs  = blockIdx.x;            // b*S + s
  const int s   = bs & (kS - 1);
  const int tok = idx[bs];
  const int t   = threadIdx.x;
#pragma unroll
  for (int r = 0; r < 2; ++r) {
    const int e = t + 256 * r;
    const int i = e >> 1;
    const float dv  = __expf((float)(2 * i) * (-9.210340371976184f / (float)kE));
    const float ang = (float)s * dv;
    const float pe  = (e & 1) ? cosf(ang) : sinf(ang);   // libm: accurate arg reduction
    X[bs * kE + e] = emb[tok * kE + e] + pe;
  }
}

// ---------------- weight transpose-cast: fp32 [K][N] -> f16 [N][K] ----------
__global__ __launch_bounds__(256) void tcast_kernel(const float* __restrict__ src,
        unsigned short* __restrict__ dst, int K, int N) {
  __shared__ float t[32][33];
  const int tid = threadIdx.x;
  const int tx = tid & 31, ty = tid >> 5;          // 32 x 8
  const int n0 = blockIdx.x * 32, k0 = blockIdx.y * 32;
#pragma unroll
  for (int p = 0; p < 4; ++p)
    t[ty + 8 * p][tx] = src[(size_t)(k0 + ty + 8 * p) * N + n0 + tx];
  __syncthreads();
#pragma unroll
  for (int p = 0; p < 4; ++p)
    dst[(size_t)(n0 + ty + 8 * p) * K + k0 + tx] = f2h(t[tx][ty + 8 * p]);
}

__global__ __launch_bounds__(256) void qkvb_kernel(const float* __restrict__ qb,
        const float* __restrict__ kb, const float* __restrict__ vb,
        float* __restrict__ dst) {
  const int i = blockIdx.x * 256 + threadIdx.x;    // grid 6 -> 1536
  dst[i] = (i < 512) ? qb[i] : ((i < 1024) ? kb[i - 512] : vb[i - 1024]);
}

// ---------------- f16 MFMA GEMM: C = act(A@B + bias [+ R]) ------------------
// A fp32 [M,K] (cast to f16 at staging), Bt f16 [N,K] (pre-transposed).
// 128x128 tile, 4 waves (2x2 quadrants of 64x64), K-step 32.
template <int RELU, int RES, int OUT16>
__global__ __launch_bounds__(256) void mfma_gemm(const float* __restrict__ A,
        const unsigned short* __restrict__ Bt, const float* __restrict__ bias,
        const float* __restrict__ Rm, void* __restrict__ Cv,
        int M, int N, int K) {
  __shared__ __align__(16) unsigned short As[128 * 40];
  __shared__ __align__(16) unsigned short Bs[128 * 40];
  const int tid = threadIdx.x;
  const int m0 = blockIdx.y * 128, n0 = blockIdx.x * 128;
  const int wid = tid >> 6, lane = tid & 63;
  const int lm = lane & 15, quad = lane >> 4;
  const int wm = (wid & 1) * 64, wn = (wid >> 1) * 64;
  const int am = tid >> 3, ak = (tid & 7) * 4;     // A staging: 32 rows/pass
  const int bn = tid >> 2, bk = (tid & 3) * 8;     // B staging: 64 rows/pass
  floatx4 acc[4][4] = {};
  for (int k0 = 0; k0 < K; k0 += 32) {
#pragma unroll
    for (int p = 0; p < 4; ++p) {
      const float4 v = *(const float4*)&A[(size_t)(m0 + am + 32 * p) * K + k0 + ak];
      ushort4 o;
      o.x = f2h(v.x); o.y = f2h(v.y); o.z = f2h(v.z); o.w = f2h(v.w);
      *(ushort4*)&As[(am + 32 * p) * 40 + ak] = o;
    }
#pragma unroll
    for (int p = 0; p < 2; ++p) {
      const uint4 v = *(const uint4*)&Bt[(size_t)(n0 + bn + 64 * p) * K + k0 + bk];
      *(uint4*)&Bs[(bn + 64 * p) * 40 + bk] = v;
    }
    __syncthreads();
    f16x8 af[4], bf[4];
#pragma unroll
    for (int t = 0; t < 4; ++t) {
      af[t] = *(const f16x8*)&As[(wm + t * 16 + lm) * 40 + quad * 8];
      bf[t] = *(const f16x8*)&Bs[(wn + t * 16 + lm) * 40 + quad * 8];
    }
#pragma unroll
    for (int mt = 0; mt < 4; ++mt)
#pragma unroll
      for (int nt = 0; nt < 4; ++nt)
        acc[mt][nt] = __builtin_amdgcn_mfma_f32_16x16x32_f16(
            af[mt], bf[nt], acc[mt][nt], 0, 0, 0);
    __syncthreads();
  }
  // epilogue: D col = lane&15 (n), row = quad*4+reg (m)
#pragma unroll
  for (int mt = 0; mt < 4; ++mt) {
#pragma unroll
    for (int nt = 0; nt < 4; ++nt) {
      const int n = n0 + wn + nt * 16 + lm;
      const float bv = bias[n];
#pragma unroll
      for (int r = 0; r < 4; ++r) {
        const int m = m0 + wm + mt * 16 + quad * 4 + r;
        float o = acc[mt][nt][r] + bv;
        if (RES) o += Rm[(size_t)m * N + n];
        if (RELU) o = fmaxf(o, 0.f);
        if (OUT16) ((unsigned short*)Cv)[(size_t)m * N + n] = f2h(o);
        else       ((float*)Cv)[(size_t)m * N + n] = o;
      }
    }
  }
}

// ---------------- window pre-sum of V (f16 in fused qkv, f16 out) -----------
__global__ __launch_bounds__(256) void vsum_kernel(const unsigned short* __restrict__ QKVh,
        unsigned short* __restrict__ VSum) {
  const int gid  = blockIdx.x * 256 + threadIdx.x;   // < B*SK*E (exact)
  const int half = kSK * kE;
  const int b = (gid >= half) ? 1 : 0;
  const int r = gid - b * half;
  const int t = r >> 9, e = r & 511;
  const unsigned short* vp = QKVh + (size_t)(b * kS + t) * kQKV + 2 * kE + e;
  const float s = h2f(vp[0]) + h2f(vp[kQKV]) + h2f(vp[2 * kQKV])
                + h2f(vp[3 * kQKV]) + h2f(vp[4 * kQKV]);
  VSum[gid] = f2h(s);
}

// ---------------- MFMA flash attention (unfold contraction) -----------------
// Block = (qt 64 queries, h, b), 4 waves; wave owns 16 score rows x 64 cols.
// LDS: Qs 68 rows (q0-2..q0+65), Ks 68 rows (t0..t0+67), Vt = Vsum^T [d][tl],
// Ps wave-private P strips. K-dim 320 = 10 k-steps of 32; chunk w reads
// Q row (m+w), K row (t+w) -- the unfold is pure addressing.
__global__ __launch_bounds__(256) void flash_kernel(const unsigned short* __restrict__ QKVh,
        const unsigned short* __restrict__ VSh, float* __restrict__ O) {
  const int tid = threadIdx.x;
  const int qt = blockIdx.x, h = blockIdx.y, b = blockIdx.z;
  const int q0 = qt * 64;
  const int wid = tid >> 6, lane = tid & 63;
  const int lm = lane & 15, quad = lane >> 4;

  __shared__ __align__(16) unsigned short Qs[68 * kSQ];
  __shared__ __align__(16) unsigned short Ks[68 * kSQ];
  __shared__ __align__(16) unsigned short Vt[64 * kSQ];
  __shared__ __align__(16) unsigned short Ps[64 * kSQ];

  // Q staging: rows i -> global q0-2+i (zero-pad OOB), f16 passthrough
  for (int id = tid; id < 68 * 16; id += 256) {
    const int row = id >> 4, c4 = (id & 15) * 4;
    const int gq = q0 - 2 + row;
    ushort4 v = make_ushort4(0, 0, 0, 0);
    if (gq >= 0 && gq < kS)
      v = *(const ushort4*)&QKVh[(size_t)(b * kS + gq) * kQKV + h * kDH + c4];
    *(ushort4*)&Qs[row * kSQ + c4] = v;
  }

  float mrow[4] = {-1e30f, -1e30f, -1e30f, -1e30f};
  float lrow[4] = {0.f, 0.f, 0.f, 0.f};
  floatx4 Oacc[4] = {};   // [nt2]: rows wid*16+quad*4+r, col nt2*16+lm

  for (int t0 = 0; t0 < kSK; t0 += 64) {          // 32 iterations
    __syncthreads();                               // prev iter Ks/Vt reads done
    for (int id = tid; id < 68 * 16; id += 256) {  // K rows t0..t0+67
      const int row = id >> 4, c4 = (id & 15) * 4;
      const int gk = t0 + row;
      ushort4 v = make_ushort4(0, 0, 0, 0);
      if (gk < kS)
        v = *(const ushort4*)&QKVh[(size_t)(b * kS + gk) * kQKV + kE + h * kDH + c4];
      *(ushort4*)&Ks[row * kSQ + c4] = v;
    }
    for (int id = tid; id < 64 * 16; id += 256) {  // Vsum^T: [d][tl]
      const int d4 = (id & 15) * 4, tl = id >> 4;
      const int gt = t0 + tl;
      ushort4 v = make_ushort4(0, 0, 0, 0);
      if (gt < kSK)
        v = *(const ushort4*)&VSh[(size_t)(b * kSK + gt) * kE + h * kDH + d4];
      Vt[(d4 + 0) * kSQ + tl] = v.x;
      Vt[(d4 + 1) * kSQ + tl] = v.y;
      Vt[(d4 + 2) * kSQ + tl] = v.z;
      Vt[(d4 + 3) * kSQ + tl] = v.w;
    }
    __syncthreads();
    // QK^T unfold: 10 k-steps (w = kk>>1, d0 = (kk&1)*32)
    floatx4 sac[4] = {};
#pragma unroll
    for (int kk = 0; kk < 10; ++kk) {
      const int w = kk >> 1, d0 = (kk & 1) * 32;
      const f16x8 af = *(const f16x8*)&Qs[(wid * 16 + lm + w) * kSQ + d0 + quad * 8];
#pragma unroll
      for (int nt = 0; nt < 4; ++nt) {
        const f16x8 bf = *(const f16x8*)&Ks[(nt * 16 + lm + w) * kSQ + d0 + quad * 8];
        sac[nt] = __builtin_amdgcn_mfma_f32_16x16x32_f16(af, bf, sac[nt], 0, 0, 0);
      }
    }
    // in-register online softmax; row m = wid*16+quad*4+r, col t0+nt*16+lm
    float p[4][4], alpha[4];
#pragma unroll
    for (int r = 0; r < 4; ++r) {
      float mx = -1e30f;
#pragma unroll
      for (int nt = 0; nt < 4; ++nt) {
        float s = sac[nt][r] * kScale;
        if (t0 + nt * 16 + lm >= kSK) s = -1e30f;
        p[nt][r] = s;
        mx = fmaxf(mx, s);
      }
      mx = fmaxf(mx, __shfl_xor(mx, 1));
      mx = fmaxf(mx, __shfl_xor(mx, 2));
      mx = fmaxf(mx, __shfl_xor(mx, 4));
      mx = fmaxf(mx, __shfl_xor(mx, 8));
      const float mnew = fmaxf(mrow[r], mx);
      alpha[r] = __expf(mrow[r] - mnew);
      float ps = 0.f;
#pragma unroll
      for (int nt = 0; nt < 4; ++nt) {
        const float e = __expf(p[nt][r] - mnew);
        p[nt][r] = e;
        ps += e;
      }
      ps += __shfl_xor(ps, 1);
      ps += __shfl_xor(ps, 2);
      ps += __shfl_xor(ps, 4);
      ps += __shfl_xor(ps, 8);
      lrow[r] = lrow[r] * alpha[r] + ps;
      mrow[r] = mnew;
    }
    // P -> wave-private LDS strip (f16), then read back as A-frags (no barrier)
#pragma unroll
    for (int r = 0; r < 4; ++r)
#pragma unroll
      for (int nt = 0; nt < 4; ++nt)
        Ps[(wid * 16 + quad * 4 + r) * kSQ + nt * 16 + lm] = f2h(p[nt][r]);
    __asm__ volatile("s_waitcnt lgkmcnt(0)" ::: "memory");
#pragma unroll
    for (int nt2 = 0; nt2 < 4; ++nt2)
#pragma unroll
      for (int r = 0; r < 4; ++r)
        Oacc[nt2][r] *= alpha[r];
#pragma unroll
    for (int k2 = 0; k2 < 2; ++k2) {
      const f16x8 pf = *(const f16x8*)&Ps[(wid * 16 + lm) * kSQ + k2 * 32 + quad * 8];
#pragma unroll
      for (int nt2 = 0; nt2 < 4; ++nt2) {
        const f16x8 vf = *(const f16x8*)&Vt[(nt2 * 16 + lm) * kSQ + k2 * 32 + quad * 8];
        Oacc[nt2] = __builtin_amdgcn_mfma_f32_16x16x32_f16(pf, vf, Oacc[nt2], 0, 0, 0);
      }
    }
  }
#pragma unroll
  for (int r = 0; r < 4; ++r) {
    const float inv = 1.f / lrow[r];
    const int q = q0 + wid * 16 + quad * 4 + r;
#pragma unroll
    for (int nt2 = 0; nt2 < 4; ++nt2)
      O[(size_t)(b * kS + q) * kE + h * kDH + nt2 * 16 + lm] = Oacc[nt2][r] * inv;
  }
}

// ---------------- layernorm over E=512 (one block per row) ------------------
__global__ __launch_bounds__(256) void ln_kernel(const float* __restrict__ Xin,
        const float* __restrict__ w, const float* __restrict__ bb,
        float* __restrict__ Y) {
  const int row = blockIdx.x;
  const int tid = threadIdx.x;
  const float* xr = Xin + (size_t)row * kE;
  const float v0 = xr[tid], v1 = xr[tid + 256];
  float s = v0 + v1, sq = v0 * v0 + v1 * v1;
  for (int off = 32; off; off >>= 1) {
    s  += __shfl_down(s, off);
    sq += __shfl_down(sq, off);
  }
  __shared__ float rs[4], rq[4];
  const int wid = tid >> 6;
  if ((tid & 63) == 0) { rs[wid] = s; rq[wid] = sq; }
  __syncthreads();
  const float St = rs[0] + rs[1] + rs[2] + rs[3];
  const float Qt = rq[0] + rq[1] + rq[2] + rq[3];
  const float mean = St * (1.f / kE);
  const float var  = Qt * (1.f / kE) - mean * mean;
  const float rstd = rsqrtf(var + 1e-5f);
  float* yr = Y + (size_t)row * kE;
  yr[tid]       = (v0 - mean) * rstd * w[tid]       + bb[tid];
  yr[tid + 256] = (v1 - mean) * rstd * w[tid + 256] + bb[tid + 256];
}

// ---------------- final head: out[b,o] = sum_k x[b,k] W[k,o] + b[o] ---------
__global__ __launch_bounds__(256) void final_kernel(const float* __restrict__ X,
        const float* __restrict__ Wt, const float* __restrict__ bias,
        float* __restrict__ out) {
  const int b = blockIdx.y, chunk = blockIdx.x;
  const int tid = threadIdx.x;
  const float* xb = X + (size_t)b * (kS * kE);
  float acc[6] = {};
  const int k0 = chunk * 8192;                     // 128 chunks * 8192 = 1M
#pragma unroll 4
  for (int i = 0; i < 32; ++i) {
    const int kk = k0 + tid + i * 256;
    const float xv = xb[kk];
    const float* wr = Wt + (size_t)kk * 6;
#pragma unroll
    for (int o = 0; o < 6; ++o) acc[o] = fmaf(xv, wr[o], acc[o]);
  }
#pragma unroll
  for (int o = 0; o < 6; ++o)
    for (int off = 32; off; off >>= 1) acc[o] += __shfl_down(acc[o], off);
  __shared__ float part[4][6];
  const int wid = tid >> 6;
  if ((tid & 63) == 0) {
#pragma unroll
    for (int o = 0; o < 6; ++o) part[wid][o] = acc[o];
  }
  __syncthreads();
  if (tid < 6) {
    float s2 = part[0][tid] + part[1][tid] + part[2][tid] + part[3][tid];
    if (chunk == 0) s2 += bias[tid];
    atomicAdd(&out[b * 6 + tid], s2);
  }
}

// ---------------------------------------------------------------------------
extern "C" void kernel_launch(void* const* d_in, const int* in_sizes, int n_in,
                              void* d_out, int out_size, void* d_ws, size_t ws_size,
                              hipStream_t stream) {
  (void)in_sizes; (void)n_in; (void)ws_size;
  const int*   tok   = (const int*)d_in[0];
  const float* emb   = (const float*)d_in[1];
  const float* ln_w  = (const float*)d_in[2];
  const float* ln_b  = (const float*)d_in[3];
  const float* q_w   = (const float*)d_in[4];
  const float* q_b   = (const float*)d_in[5];
  const float* k_w   = (const float*)d_in[6];
  const float* k_b   = (const float*)d_in[7];
  const float* v_w   = (const float*)d_in[8];
  const float* v_b   = (const float*)d_in[9];
  const float* fc1_w = (const float*)d_in[10];
  const float* fc1_b = (const float*)d_in[11];
  const float* fc2_w = (const float*)d_in[12];
  const float* fc2_b = (const float*)d_in[13];
  const float* out_w = (const float*)d_in[14];
  const float* out_b = (const float*)d_in[15];

  // workspace (floats): x | y | regA(8.39M floats) | f16 weights | qkv bias.
  // regA holds qkvh (f16 [4096][1536]) + vsh (f16 [B,SK,512]); hbuf (fp32
  // [4096][2048]) aliases the same region -- qkvh/vsh are dead by fc1.
  float* ws   = (float*)d_ws;
  float* x    = ws;
  float* y    = ws + (size_t)1 * kNX;
  float* regA = ws + (size_t)2 * kNX;
  unsigned short* qkvh = (unsigned short*)regA;                    // 3.15M ush
  unsigned short* vsh  = (unsigned short*)(regA + (size_t)kTok * kQKV / 2);
  float* hbuf = regA;                                              // [4096][2048]
  unsigned short* wqkvT = (unsigned short*)(ws + (size_t)6 * kNX); // [1536][512]
  unsigned short* fc1T  = wqkvT + (size_t)kQKV * kE;               // [2048][512]
  unsigned short* fc2T  = fc1T + (size_t)kHID * kE;                // [512][2048]
  float* qkvb = (float*)(fc2T + (size_t)kE * kHID);                // [1536]

  // per-launch weight prep (graph-safe, no static guards)
  tcast_kernel<<<dim3(16, 16), 256, 0, stream>>>(q_w, wqkvT, kE, kE);
  tcast_kernel<<<dim3(16, 16), 256, 0, stream>>>(k_w, wqkvT + (size_t)kE * kE, kE, kE);
  tcast_kernel<<<dim3(16, 16), 256, 0, stream>>>(v_w, wqkvT + (size_t)2 * kE * kE, kE, kE);
  tcast_kernel<<<dim3(64, 16), 256, 0, stream>>>(fc1_w, fc1T, kE, kHID);
  tcast_kernel<<<dim3(16, 64), 256, 0, stream>>>(fc2_w, fc2T, kHID, kE);
  qkvb_kernel<<<dim3(6), 256, 0, stream>>>(q_b, k_b, v_b, qkvb);

  embed_kernel<<<dim3(kTok), 256, 0, stream>>>(tok, emb, x);
  for (int l = 0; l < kL; ++l) {
    mfma_gemm<0, 0, 1><<<dim3(kQKV / 128, kTok / 128), 256, 0, stream>>>(
        x, wqkvT, qkvb, nullptr, qkvh, kTok, kQKV, kE);
    vsum_kernel<<<dim3((kB * kSK * kE) / 256), 256, 0, stream>>>(qkvh, vsh);
    flash_kernel<<<dim3(kS / 64, kH, kB), 256, 0, stream>>>(qkvh, vsh, y);
    ln_kernel<<<dim3(kTok), 256, 0, stream>>>(y, ln_w, ln_b, x);
    mfma_gemm<1, 0, 0><<<dim3(kHID / 128, kTok / 128), 256, 0, stream>>>(
        x, fc1T, fc1_b, nullptr, hbuf, kTok, kHID, kE);
    mfma_gemm<0, 1, 0><<<dim3(kE / 128, kTok / 128), 256, 0, stream>>>(
        hbuf, fc2T, fc2_b, x, y, kTok, kE, kHID);
    ln_kernel<<<dim3(kTok), 256, 0, stream>>>(y, ln_w, ln_b, x);
  }
  hipMemsetAsync(d_out, 0, (size_t)out_size * sizeof(float), stream);
  final_kernel<<<dim3(128, kB), 256, 0, stream>>>(x, out_w, out_b, (float*)d_out);
}